// Round 2
// baseline (3487.385 us; speedup 1.0000x reference)
//
#include <hip/hip_runtime.h>
#include <math.h>

#define DIM 128
#define NEG 0.2f
#define EPS 1e-5f

static __device__ __forceinline__ float leaky(float a) { return a > 0.f ? a : NEG * a; }
static __device__ __forceinline__ float bf2f(unsigned short u) {
    return __uint_as_float(((unsigned int)u) << 16);
}
static __device__ __forceinline__ unsigned short f2bf(float f) {
    unsigned int u = __float_as_uint(f);
    unsigned int r = (u + 0x7fffu + ((u >> 16) & 1u)) >> 16;  // RNE
    return (unsigned short)r;
}

// ---------------- K1: h = x@W (bf16 packed out), plus a_src/a_dst head dots --
// Block = 1024 threads = 16 waves. Each block: 64 rows x 64 cols (one half).
// LDS: W-half 32KB + per-wave x staging 32KB = 64KB -> 2 blocks/CU if VGPR<=64.
__global__ __launch_bounds__(1024, 8) void k_gemm(const float* __restrict__ x,
                                                  const float* __restrict__ W,
                                                  const float* __restrict__ att_s,
                                                  const float* __restrict__ att_d,
                                                  unsigned short* __restrict__ hpk,
                                                  float* __restrict__ asrc,
                                                  float* __restrict__ adst, int n) {
    const int half = blockIdx.x & 1;
    const int rb = blockIdx.x >> 1;
    __shared__ float Ws[DIM][64];     // Ws[k][c] = W[k][half*64+c], 32 KB
    __shared__ float4 xs[16][4][32];  // per-wave 4 rows of x, 32 KB
    for (int idx = threadIdx.x; idx < DIM * 64; idx += 1024) {
        int k = idx >> 6, c = idx & 63;
        Ws[k][c] = W[k * DIM + half * 64 + c];
    }
    const int w = threadIdx.x >> 6;
    const int lane = threadIdx.x & 63;
    const int col = half * 64 + lane;
    const float as = att_s[col];
    const float ad = att_d[col];
    const int r0 = rb * 64 + w * 4;
    {   // coalesced stage of 4 rows: flat float4 f: row=f>>5, c4=f&31
        int f0 = lane, f1 = 64 + lane;
        int ra = min(r0 + (f0 >> 5), n - 1);
        int rc = min(r0 + (f1 >> 5), n - 1);
        xs[w][f0 >> 5][f0 & 31] = ((const float4*)x)[(size_t)ra * 32 + (f0 & 31)];
        xs[w][f1 >> 5][f1 & 31] = ((const float4*)x)[(size_t)rc * 32 + (f1 & 31)];
    }
    __syncthreads();
    float acc0 = 0.f, acc1 = 0.f, acc2 = 0.f, acc3 = 0.f;
    for (int k4 = 0; k4 < 32; ++k4) {
        float4 xv0 = xs[w][0][k4];
        float4 xv1 = xs[w][1][k4];
        float4 xv2 = xs[w][2][k4];
        float4 xv3 = xs[w][3][k4];
#pragma unroll
        for (int kk = 0; kk < 4; ++kk) {
            float wv = Ws[k4 * 4 + kk][lane];
            acc0 = fmaf(((const float*)&xv0)[kk], wv, acc0);
            acc1 = fmaf(((const float*)&xv1)[kk], wv, acc1);
            acc2 = fmaf(((const float*)&xv2)[kk], wv, acc2);
            acc3 = fmaf(((const float*)&xv3)[kk], wv, acc3);
        }
    }
    float accs[4] = {acc0, acc1, acc2, acc3};
#pragma unroll
    for (int rr = 0; rr < 4; ++rr) {
        int r = r0 + rr;
        if (r >= n) break;  // wave-uniform
        float hv = accs[rr];
        float p = hv * as, q = hv * ad;
#pragma unroll
        for (int m = 1; m < 32; m <<= 1) {
            p += __shfl_xor(p, m);
            q += __shfl_xor(q, m);
        }
        // packed layout: word j*64+l holds {chan l (lo), chan l+64 (hi)}
        hpk[((size_t)r * 64 + lane) * 2 + half] = f2bf(hv);
        if (lane == 0) {
            asrc[r * 4 + half * 2] = p;
            adst[r * 4 + half * 2] = q;
        } else if (lane == 32) {
            asrc[r * 4 + half * 2 + 1] = p;
            adst[r * 4 + half * 2 + 1] = q;
        }
    }
}

// ---------------- K2: init deg=1 (self loop) and zero BN stats ----------------
__global__ void k_init(int* __restrict__ deg, float* __restrict__ stats, int n) {
    int t = blockIdx.x * blockDim.x + threadIdx.x;
    if (t < n) deg[t] = 1;
    if (t < 256) stats[t] = 0.f;
}

// ---------------- K3: histogram of dst ----------------
__global__ void k_hist(const int* __restrict__ dst, int* __restrict__ deg, int E) {
    int t = blockIdx.x * blockDim.x + threadIdx.x;
    if (t < E) atomicAdd(&deg[dst[t]], 1);
}

// ---------------- K4: single-block exclusive scan over deg ----------------
__global__ __launch_bounds__(1024) void k_scan(const int* __restrict__ deg,
                                               int* __restrict__ row_start,
                                               int* __restrict__ cursor, int n) {
    __shared__ int lds[1024];
    int tid = threadIdx.x;
    int chunk = (n + 1023) >> 10;
    int beg = tid * chunk, end = min(beg + chunk, n);
    int s = 0;
    for (int i = beg; i < end; ++i) s += deg[i];
    lds[tid] = s;
    __syncthreads();
    int v = s;
    for (int ofs = 1; ofs < 1024; ofs <<= 1) {
        int t = (tid >= ofs) ? lds[tid - ofs] : 0;
        __syncthreads();
        v += t;
        lds[tid] = v;
        __syncthreads();
    }
    int excl = v - s;
    for (int i = beg; i < end; ++i) {
        row_start[i] = excl;
        cursor[i] = excl;
        excl += deg[i];
    }
    if (tid == 1023) row_start[n] = v;  // total = E + n
}

// ---------------- K5: scatter edges (and self loops) into CSR ----------------
__global__ void k_scatter(const int* __restrict__ src, const int* __restrict__ dst,
                          int* __restrict__ cursor, int* __restrict__ csr, int E, int n) {
    int t = blockIdx.x * blockDim.x + threadIdx.x;
    if (t < E) {
        int d = dst[t];
        int slot = atomicAdd(&cursor[d], 1);
        csr[slot] = src[t];
    } else if (t < E + n) {
        int i = t - E;
        int slot = atomicAdd(&cursor[i], 1);
        csr[slot] = i;
    }
}

// ---------------- K6: per-dst-node online-softmax aggregation + residual + bias
//                      + BN partial stats. One wave per node. ----------------
__global__ __launch_bounds__(256) void k_agg(const unsigned short* __restrict__ hpk,
                                             const float* __restrict__ asrc,
                                             const float* __restrict__ adst,
                                             const int* __restrict__ row_start,
                                             const int* __restrict__ csr,
                                             const float* __restrict__ prev,
                                             const float* __restrict__ bias,
                                             float* __restrict__ ypre,
                                             float* __restrict__ stats, int n) {
    const int lane = threadIdx.x & 63;
    const int hh = lane >> 5;  // head selector: chans (lane, lane+64) -> heads (hh, 2+hh)
    const unsigned int* __restrict__ hw = (const unsigned int*)hpk;
    int wave = blockIdx.x * 4 + (threadIdx.x >> 6);
    int nw = gridDim.x * 4;
    const float b0 = bias[lane], b1 = bias[64 + lane];
    float bsum0 = 0.f, bsq0 = 0.f, bsum1 = 0.f, bsq1 = 0.f;
    for (int i0 = wave; i0 < n; i0 += nw) {
        int i = __builtin_amdgcn_readfirstlane(i0);
        int e0 = row_start[i], e1 = row_start[i + 1];
        float adx0 = adst[i * 4 + hh];
        float adx1 = adst[i * 4 + 2 + hh];
        float m0 = -1e30f, m1 = -1e30f, s0 = 0.f, s1 = 0.f, acc0 = 0.f, acc1 = 0.f;
        for (int e = e0; e < e1; ++e) {
            int j = csr[e];
            float al0 = leaky(asrc[j * 4 + hh] + adx0);
            float al1 = leaky(asrc[j * 4 + 2 + hh] + adx1);
            unsigned int hp = hw[(size_t)j * 64 + lane];
            float h0 = bf2f((unsigned short)(hp & 0xffffu));
            float h1 = bf2f((unsigned short)(hp >> 16));
            float mn0 = fmaxf(m0, al0);
            float sc0 = __expf(m0 - mn0);
            float p0 = __expf(al0 - mn0);
            s0 = s0 * sc0 + p0;
            acc0 = fmaf(acc0, sc0, p0 * h0);
            m0 = mn0;
            float mn1 = fmaxf(m1, al1);
            float sc1 = __expf(m1 - mn1);
            float p1 = __expf(al1 - mn1);
            s1 = s1 * sc1 + p1;
            acc1 = fmaf(acc1, sc1, p1 * h1);
            m1 = mn1;
        }
        float o0 = acc0 / s0 + b0 + prev[(size_t)i * DIM + lane];
        float o1 = acc1 / s1 + b1 + prev[(size_t)i * DIM + 64 + lane];
        ypre[(size_t)i * DIM + lane] = o0;
        ypre[(size_t)i * DIM + 64 + lane] = o1;
        bsum0 += o0; bsq0 = fmaf(o0, o0, bsq0);
        bsum1 += o1; bsq1 = fmaf(o1, o1, bsq1);
    }
    __shared__ float red[4][256];
    red[0][threadIdx.x] = bsum0;
    red[1][threadIdx.x] = bsq0;
    red[2][threadIdx.x] = bsum1;
    red[3][threadIdx.x] = bsq1;
    __syncthreads();
    if (threadIdx.x < 64) {
        int t = threadIdx.x;
        float v0 = red[0][t] + red[0][t + 64] + red[0][t + 128] + red[0][t + 192];
        float v1 = red[1][t] + red[1][t + 64] + red[1][t + 128] + red[1][t + 192];
        float v2 = red[2][t] + red[2][t + 64] + red[2][t + 128] + red[2][t + 192];
        float v3 = red[3][t] + red[3][t + 64] + red[3][t + 128] + red[3][t + 192];
        atomicAdd(&stats[t], v0);        // sum, channel t
        atomicAdd(&stats[64 + t], v2);   // sum, channel 64+t
        atomicAdd(&stats[128 + t], v1);  // sumsq, channel t
        atomicAdd(&stats[192 + t], v3);  // sumsq, channel 64+t
    }
}

// ---------------- K7: finalize BN scale/shift ----------------
__global__ void k_bnfin(const float* __restrict__ stats, const float* __restrict__ gamma,
                        const float* __restrict__ beta, float* __restrict__ AB, int n) {
    int c = threadIdx.x;  // 128 threads
    float fn = (float)n;
    float mean = stats[c] / fn;
    float var = stats[128 + c] / fn - mean * mean;
    float a = gamma[c] * rsqrtf(var + EPS);
    AB[c] = a;
    AB[128 + c] = beta[c] - mean * a;
}

// ---------------- K8: y = relu(y*A + B), in place, float4 ----------------
__global__ __launch_bounds__(256) void k_final(float* __restrict__ y,
                                               const float* __restrict__ AB, int total4) {
    int t0 = blockIdx.x * blockDim.x + threadIdx.x;
    int stride = gridDim.x * blockDim.x;
    for (int t = t0; t < total4; t += stride) {
        float4 v = ((float4*)y)[t];
        int c0 = (t * 4) & 127;
        v.x = fmaf(v.x, AB[c0 + 0], AB[128 + c0 + 0]);
        v.y = fmaf(v.y, AB[c0 + 1], AB[128 + c0 + 1]);
        v.z = fmaf(v.z, AB[c0 + 2], AB[128 + c0 + 2]);
        v.w = fmaf(v.w, AB[c0 + 3], AB[128 + c0 + 3]);
        v.x = v.x > 0.f ? v.x : 0.f;
        v.y = v.y > 0.f ? v.y : 0.f;
        v.z = v.z > 0.f ? v.z : 0.f;
        v.w = v.w > 0.f ? v.w : 0.f;
        ((float4*)y)[t] = v;
    }
}

extern "C" void kernel_launch(void* const* d_in, const int* in_sizes, int n_in,
                              void* d_out, int out_size, void* d_ws, size_t ws_size,
                              hipStream_t stream) {
    const float* prev  = (const float*)d_in[0];
    const float* x     = (const float*)d_in[1];
    const int*   ei    = (const int*)d_in[2];
    const float* W     = (const float*)d_in[3];
    const float* att_s = (const float*)d_in[4];
    const float* att_d = (const float*)d_in[5];
    const float* bias  = (const float*)d_in[6];
    const float* gamma = (const float*)d_in[7];
    const float* beta  = (const float*)d_in[8];
    const int n = in_sizes[0] / DIM;
    const int E = in_sizes[2] / 2;
    const int* src = ei;
    const int* dst = ei + E;

    char* p = (char*)d_ws;
    auto alloc = [&](size_t bytes) {
        void* q = (void*)p;
        p += (bytes + 255) & ~(size_t)255;
        return q;
    };
    unsigned short* hpk = (unsigned short*)alloc((size_t)n * DIM * 2);
    float* asrc      = (float*)alloc((size_t)n * 4 * 4);
    float* adst      = (float*)alloc((size_t)n * 4 * 4);
    int*   deg       = (int*)alloc((size_t)(n + 1) * 4);
    int*   row_start = (int*)alloc((size_t)(n + 1) * 4);
    int*   cursor    = (int*)alloc((size_t)(n + 1) * 4);
    int*   csr       = (int*)alloc((size_t)(E + n) * 4);
    float* stats     = (float*)alloc(256 * 4);
    float* AB        = (float*)alloc(256 * 4);
    float* yout      = (float*)d_out;

    int nrb = (n + 63) / 64;
    k_init<<<dim3((n + 255) / 256), dim3(256), 0, stream>>>(deg, stats, n);
    k_gemm<<<dim3(nrb * 2), dim3(1024), 0, stream>>>(x, W, att_s, att_d, hpk, asrc, adst, n);
    k_hist<<<dim3((E + 255) / 256), dim3(256), 0, stream>>>(dst, deg, E);
    k_scan<<<dim3(1), dim3(1024), 0, stream>>>(deg, row_start, cursor, n);
    k_scatter<<<dim3((E + n + 255) / 256), dim3(256), 0, stream>>>(src, dst, cursor, csr, E, n);
    k_agg<<<dim3(2048), dim3(256), 0, stream>>>(hpk, asrc, adst, row_start, csr, prev, bias, yout, stats, n);
    k_bnfin<<<dim3(1), dim3(128), 0, stream>>>(stats, gamma, beta, AB, n);
    int total4 = n * DIM / 4;
    k_final<<<dim3(2048), dim3(256), 0, stream>>>(yout, AB, total4);
}

// Round 3
// 692.120 us; speedup vs baseline: 5.0387x; 5.0387x over previous
//
#include <hip/hip_runtime.h>
#include <math.h>

#define DIM 128
#define NEG 0.2f
#define EPS 1e-5f

static __device__ __forceinline__ float leaky(float a) { return a > 0.f ? a : NEG * a; }
static __device__ __forceinline__ float bf2f(unsigned short u) {
    return __uint_as_float(((unsigned int)u) << 16);
}
static __device__ __forceinline__ unsigned short f2bf(float f) {
    unsigned int u = __float_as_uint(f);
    unsigned int r = (u + 0x7fffu + ((u >> 16) & 1u)) >> 16;  // RNE
    return (unsigned short)r;
}

// ---------------- K1: h = x@W, bf16x2-packed dword out, + a_src/a_dst dots --
// Block = 512 threads = 8 waves; each wave does 4 rows x all 128 cols.
// Lane l holds channel pair {l, l+64} -> one packed uint store per row.
// LDS: Ws float2[128][64] = 64KB + xs 16KB = 80KB -> 2 blocks/CU.
__global__ __launch_bounds__(512, 4) void k_gemm(const float* __restrict__ x,
                                                 const float* __restrict__ W,
                                                 const float* __restrict__ att_s,
                                                 const float* __restrict__ att_d,
                                                 unsigned int* __restrict__ hpk,
                                                 float* __restrict__ asrc,
                                                 float* __restrict__ adst, int n) {
    __shared__ float2 Ws[DIM][64];   // Ws[k][c] = {W[k][c], W[k][c+64]}
    __shared__ float4 xs[8][4][32];  // per-wave 4 staged rows of x
    for (int idx = threadIdx.x; idx < DIM * 64; idx += 512) {
        int k = idx >> 6, c = idx & 63;
        Ws[k][c] = make_float2(W[k * DIM + c], W[k * DIM + 64 + c]);
    }
    const int w = threadIdx.x >> 6;
    const int lane = threadIdx.x & 63;
    const float as0 = att_s[lane], as1 = att_s[64 + lane];
    const float ad0 = att_d[lane], ad1 = att_d[64 + lane];
    const int r0 = blockIdx.x * 32 + w * 4;
    {   // coalesced stage: wave reads 2x 1KB contiguous (rows r0..r0+3)
        int f0 = lane, f1 = 64 + lane;
        int ra = min(r0 + (f0 >> 5), n - 1);
        int rc = min(r0 + (f1 >> 5), n - 1);
        xs[w][f0 >> 5][f0 & 31] = ((const float4*)x)[(size_t)ra * 32 + (f0 & 31)];
        xs[w][f1 >> 5][f1 & 31] = ((const float4*)x)[(size_t)rc * 32 + (f1 & 31)];
    }
    __syncthreads();
    float a00 = 0.f, a01 = 0.f, a10 = 0.f, a11 = 0.f;
    float a20 = 0.f, a21 = 0.f, a30 = 0.f, a31 = 0.f;
    for (int k4 = 0; k4 < 32; ++k4) {
        float4 xv0 = xs[w][0][k4];
        float4 xv1 = xs[w][1][k4];
        float4 xv2 = xs[w][2][k4];
        float4 xv3 = xs[w][3][k4];
#pragma unroll
        for (int kk = 0; kk < 4; ++kk) {
            float2 wv = Ws[k4 * 4 + kk][lane];
            float x0 = ((const float*)&xv0)[kk];
            float x1 = ((const float*)&xv1)[kk];
            float x2 = ((const float*)&xv2)[kk];
            float x3 = ((const float*)&xv3)[kk];
            a00 = fmaf(x0, wv.x, a00); a01 = fmaf(x0, wv.y, a01);
            a10 = fmaf(x1, wv.x, a10); a11 = fmaf(x1, wv.y, a11);
            a20 = fmaf(x2, wv.x, a20); a21 = fmaf(x2, wv.y, a21);
            a30 = fmaf(x3, wv.x, a30); a31 = fmaf(x3, wv.y, a31);
        }
    }
    float accs0[4] = {a00, a10, a20, a30};  // channel `lane`
    float accs1[4] = {a01, a11, a21, a31};  // channel `lane+64`
#pragma unroll
    for (int rr = 0; rr < 4; ++rr) {
        int r = r0 + rr;
        if (r >= n) break;  // wave-uniform
        float h0 = accs0[rr], h1 = accs1[rr];
        float p0 = h0 * as0, p1 = h1 * as1;
        float q0 = h0 * ad0, q1 = h1 * ad1;
#pragma unroll
        for (int m = 1; m < 32; m <<= 1) {
            p0 += __shfl_xor(p0, m);
            p1 += __shfl_xor(p1, m);
            q0 += __shfl_xor(q0, m);
            q1 += __shfl_xor(q1, m);
        }
        // dense coalesced dword store: word r*64+l = {chan l (lo), chan l+64 (hi)}
        hpk[(size_t)r * 64 + lane] = (unsigned int)f2bf(h0) | ((unsigned int)f2bf(h1) << 16);
        // heads: lanes 0-31 -> heads {0,2}; lanes 32-63 -> heads {1,3}
        if (lane == 0) {
            asrc[r * 4 + 0] = p0; asrc[r * 4 + 2] = p1;
            adst[r * 4 + 0] = q0; adst[r * 4 + 2] = q1;
        } else if (lane == 32) {
            asrc[r * 4 + 1] = p0; asrc[r * 4 + 3] = p1;
            adst[r * 4 + 1] = q0; adst[r * 4 + 3] = q1;
        }
    }
}

// ---------------- K2: init deg=1 (self loop) and zero BN stats ----------------
__global__ void k_init(int* __restrict__ deg, float* __restrict__ stats, int n) {
    int t = blockIdx.x * blockDim.x + threadIdx.x;
    if (t < n) deg[t] = 1;
    if (t < 256) stats[t] = 0.f;
}

// ---------------- K3: histogram of dst ----------------
__global__ void k_hist(const int* __restrict__ dst, int* __restrict__ deg, int E) {
    int t = blockIdx.x * blockDim.x + threadIdx.x;
    if (t < E) atomicAdd(&deg[dst[t]], 1);
}

// ---------------- K4: single-block exclusive scan over deg ----------------
__global__ __launch_bounds__(1024) void k_scan(const int* __restrict__ deg,
                                               int* __restrict__ row_start,
                                               int* __restrict__ cursor, int n) {
    __shared__ int lds[1024];
    int tid = threadIdx.x;
    int chunk = (n + 1023) >> 10;
    int beg = tid * chunk, end = min(beg + chunk, n);
    int s = 0;
    for (int i = beg; i < end; ++i) s += deg[i];
    lds[tid] = s;
    __syncthreads();
    int v = s;
    for (int ofs = 1; ofs < 1024; ofs <<= 1) {
        int t = (tid >= ofs) ? lds[tid - ofs] : 0;
        __syncthreads();
        v += t;
        lds[tid] = v;
        __syncthreads();
    }
    int excl = v - s;
    for (int i = beg; i < end; ++i) {
        row_start[i] = excl;
        cursor[i] = excl;
        excl += deg[i];
    }
    if (tid == 1023) row_start[n] = v;  // total = E + n
}

// ---------------- K5: scatter edges (and self loops) into CSR ----------------
__global__ void k_scatter(const int* __restrict__ src, const int* __restrict__ dst,
                          int* __restrict__ cursor, int* __restrict__ csr, int E, int n) {
    int t = blockIdx.x * blockDim.x + threadIdx.x;
    if (t < E) {
        int d = dst[t];
        int slot = atomicAdd(&cursor[d], 1);
        csr[slot] = src[t];
    } else if (t < E + n) {
        int i = t - E;
        int slot = atomicAdd(&cursor[i], 1);
        csr[slot] = i;
    }
}

// ---------------- K6: per-dst-node online-softmax aggregation + residual + bias
//                      + BN partial stats. One wave per node. ----------------
__global__ __launch_bounds__(256) void k_agg(const unsigned int* __restrict__ hw,
                                             const float* __restrict__ asrc,
                                             const float* __restrict__ adst,
                                             const int* __restrict__ row_start,
                                             const int* __restrict__ csr,
                                             const float* __restrict__ prev,
                                             const float* __restrict__ bias,
                                             float* __restrict__ ypre,
                                             float* __restrict__ stats, int n) {
    const int lane = threadIdx.x & 63;
    const int hh = lane >> 5;  // head selector: chans (lane, lane+64) -> heads (hh, 2+hh)
    int wave = blockIdx.x * 4 + (threadIdx.x >> 6);
    int nw = gridDim.x * 4;
    const float b0 = bias[lane], b1 = bias[64 + lane];
    float bsum0 = 0.f, bsq0 = 0.f, bsum1 = 0.f, bsq1 = 0.f;
    for (int i0 = wave; i0 < n; i0 += nw) {
        int i = __builtin_amdgcn_readfirstlane(i0);
        int e0 = row_start[i], e1 = row_start[i + 1];
        float adx0 = adst[i * 4 + hh];
        float adx1 = adst[i * 4 + 2 + hh];
        float m0 = -1e30f, m1 = -1e30f, s0 = 0.f, s1 = 0.f, acc0 = 0.f, acc1 = 0.f;
        for (int e = e0; e < e1; ++e) {
            int j = csr[e];
            float al0 = leaky(asrc[j * 4 + hh] + adx0);
            float al1 = leaky(asrc[j * 4 + 2 + hh] + adx1);
            unsigned int hp = hw[(size_t)j * 64 + lane];
            float h0 = bf2f((unsigned short)(hp & 0xffffu));
            float h1 = bf2f((unsigned short)(hp >> 16));
            float mn0 = fmaxf(m0, al0);
            float sc0 = __expf(m0 - mn0);
            float p0 = __expf(al0 - mn0);
            s0 = s0 * sc0 + p0;
            acc0 = fmaf(acc0, sc0, p0 * h0);
            m0 = mn0;
            float mn1 = fmaxf(m1, al1);
            float sc1 = __expf(m1 - mn1);
            float p1 = __expf(al1 - mn1);
            s1 = s1 * sc1 + p1;
            acc1 = fmaf(acc1, sc1, p1 * h1);
            m1 = mn1;
        }
        float o0 = acc0 / s0 + b0 + prev[(size_t)i * DIM + lane];
        float o1 = acc1 / s1 + b1 + prev[(size_t)i * DIM + 64 + lane];
        ypre[(size_t)i * DIM + lane] = o0;
        ypre[(size_t)i * DIM + 64 + lane] = o1;
        bsum0 += o0; bsq0 = fmaf(o0, o0, bsq0);
        bsum1 += o1; bsq1 = fmaf(o1, o1, bsq1);
    }
    __shared__ float red[4][256];
    red[0][threadIdx.x] = bsum0;
    red[1][threadIdx.x] = bsq0;
    red[2][threadIdx.x] = bsum1;
    red[3][threadIdx.x] = bsq1;
    __syncthreads();
    if (threadIdx.x < 64) {
        int t = threadIdx.x;
        float v0 = red[0][t] + red[0][t + 64] + red[0][t + 128] + red[0][t + 192];
        float v1 = red[1][t] + red[1][t + 64] + red[1][t + 128] + red[1][t + 192];
        float v2 = red[2][t] + red[2][t + 64] + red[2][t + 128] + red[2][t + 192];
        float v3 = red[3][t] + red[3][t + 64] + red[3][t + 128] + red[3][t + 192];
        atomicAdd(&stats[t], v0);        // sum, channel t
        atomicAdd(&stats[64 + t], v2);   // sum, channel 64+t
        atomicAdd(&stats[128 + t], v1);  // sumsq, channel t
        atomicAdd(&stats[192 + t], v3);  // sumsq, channel 64+t
    }
}

// ---------------- K7: finalize BN scale/shift ----------------
__global__ void k_bnfin(const float* __restrict__ stats, const float* __restrict__ gamma,
                        const float* __restrict__ beta, float* __restrict__ AB, int n) {
    int c = threadIdx.x;  // 128 threads
    float fn = (float)n;
    float mean = stats[c] / fn;
    float var = stats[128 + c] / fn - mean * mean;
    float a = gamma[c] * rsqrtf(var + EPS);
    AB[c] = a;
    AB[128 + c] = beta[c] - mean * a;
}

// ---------------- K8: y = relu(y*A + B), in place, float4 ----------------
__global__ __launch_bounds__(256) void k_final(float* __restrict__ y,
                                               const float* __restrict__ AB, int total4) {
    int t0 = blockIdx.x * blockDim.x + threadIdx.x;
    int stride = gridDim.x * blockDim.x;
    for (int t = t0; t < total4; t += stride) {
        float4 v = ((float4*)y)[t];
        int c0 = (t * 4) & 127;
        v.x = fmaf(v.x, AB[c0 + 0], AB[128 + c0 + 0]);
        v.y = fmaf(v.y, AB[c0 + 1], AB[128 + c0 + 1]);
        v.z = fmaf(v.z, AB[c0 + 2], AB[128 + c0 + 2]);
        v.w = fmaf(v.w, AB[c0 + 3], AB[128 + c0 + 3]);
        v.x = v.x > 0.f ? v.x : 0.f;
        v.y = v.y > 0.f ? v.y : 0.f;
        v.z = v.z > 0.f ? v.z : 0.f;
        v.w = v.w > 0.f ? v.w : 0.f;
        ((float4*)y)[t] = v;
    }
}

extern "C" void kernel_launch(void* const* d_in, const int* in_sizes, int n_in,
                              void* d_out, int out_size, void* d_ws, size_t ws_size,
                              hipStream_t stream) {
    const float* prev  = (const float*)d_in[0];
    const float* x     = (const float*)d_in[1];
    const int*   ei    = (const int*)d_in[2];
    const float* W     = (const float*)d_in[3];
    const float* att_s = (const float*)d_in[4];
    const float* att_d = (const float*)d_in[5];
    const float* bias  = (const float*)d_in[6];
    const float* gamma = (const float*)d_in[7];
    const float* beta  = (const float*)d_in[8];
    const int n = in_sizes[0] / DIM;
    const int E = in_sizes[2] / 2;
    const int* src = ei;
    const int* dst = ei + E;

    char* p = (char*)d_ws;
    auto alloc = [&](size_t bytes) {
        void* q = (void*)p;
        p += (bytes + 255) & ~(size_t)255;
        return q;
    };
    unsigned int* hpk = (unsigned int*)alloc((size_t)n * 64 * 4);
    float* asrc      = (float*)alloc((size_t)n * 4 * 4);
    float* adst      = (float*)alloc((size_t)n * 4 * 4);
    int*   deg       = (int*)alloc((size_t)(n + 1) * 4);
    int*   row_start = (int*)alloc((size_t)(n + 1) * 4);
    int*   cursor    = (int*)alloc((size_t)(n + 1) * 4);
    int*   csr       = (int*)alloc((size_t)(E + n) * 4);
    float* stats     = (float*)alloc(256 * 4);
    float* AB        = (float*)alloc(256 * 4);
    float* yout      = (float*)d_out;

    k_init<<<dim3((n + 255) / 256), dim3(256), 0, stream>>>(deg, stats, n);
    k_gemm<<<dim3((n + 31) / 32), dim3(512), 0, stream>>>(x, W, att_s, att_d, hpk, asrc, adst, n);
    k_hist<<<dim3((E + 255) / 256), dim3(256), 0, stream>>>(dst, deg, E);
    k_scan<<<dim3(1), dim3(1024), 0, stream>>>(deg, row_start, cursor, n);
    k_scatter<<<dim3((E + n + 255) / 256), dim3(256), 0, stream>>>(src, dst, cursor, csr, E, n);
    k_agg<<<dim3(2048), dim3(256), 0, stream>>>(hpk, asrc, adst, row_start, csr, prev, bias, yout, stats, n);
    k_bnfin<<<dim3(1), dim3(128), 0, stream>>>(stats, gamma, beta, AB, n);
    int total4 = n * DIM / 4;
    k_final<<<dim3(2048), dim3(256), 0, stream>>>(yout, AB, total4);
}

// Round 4
// 475.544 us; speedup vs baseline: 7.3335x; 1.4554x over previous
//
#include <hip/hip_runtime.h>
#include <math.h>

#define DIM 128
#define NEG 0.2f
#define EPS 1e-5f

static __device__ __forceinline__ float leaky(float a) { return a > 0.f ? a : NEG * a; }
static __device__ __forceinline__ float bf2f(unsigned short u) {
    return __uint_as_float(((unsigned int)u) << 16);
}
static __device__ __forceinline__ unsigned short f2bf(float f) {
    unsigned int u = __float_as_uint(f);
    unsigned int r = (u + 0x7fffu + ((u >> 16) & 1u)) >> 16;  // RNE
    return (unsigned short)r;
}

// ---------------- K1: h = x@W, bf16x2-packed dword out, + a_src/a_dst dots --
__global__ __launch_bounds__(512, 4) void k_gemm(const float* __restrict__ x,
                                                 const float* __restrict__ W,
                                                 const float* __restrict__ att_s,
                                                 const float* __restrict__ att_d,
                                                 unsigned int* __restrict__ hpk,
                                                 float* __restrict__ asrc,
                                                 float* __restrict__ adst, int n) {
    __shared__ float2 Ws[DIM][64];   // Ws[k][c] = {W[k][c], W[k][c+64]}
    __shared__ float4 xs[8][4][32];  // per-wave 4 staged rows of x
    for (int idx = threadIdx.x; idx < DIM * 64; idx += 512) {
        int k = idx >> 6, c = idx & 63;
        Ws[k][c] = make_float2(W[k * DIM + c], W[k * DIM + 64 + c]);
    }
    const int w = threadIdx.x >> 6;
    const int lane = threadIdx.x & 63;
    const float as0 = att_s[lane], as1 = att_s[64 + lane];
    const float ad0 = att_d[lane], ad1 = att_d[64 + lane];
    const int r0 = blockIdx.x * 32 + w * 4;
    {   // coalesced stage: wave reads 2x 1KB contiguous (rows r0..r0+3)
        int f0 = lane, f1 = 64 + lane;
        int ra = min(r0 + (f0 >> 5), n - 1);
        int rc = min(r0 + (f1 >> 5), n - 1);
        xs[w][f0 >> 5][f0 & 31] = ((const float4*)x)[(size_t)ra * 32 + (f0 & 31)];
        xs[w][f1 >> 5][f1 & 31] = ((const float4*)x)[(size_t)rc * 32 + (f1 & 31)];
    }
    __syncthreads();
    float a00 = 0.f, a01 = 0.f, a10 = 0.f, a11 = 0.f;
    float a20 = 0.f, a21 = 0.f, a30 = 0.f, a31 = 0.f;
    for (int k4 = 0; k4 < 32; ++k4) {
        float4 xv0 = xs[w][0][k4];
        float4 xv1 = xs[w][1][k4];
        float4 xv2 = xs[w][2][k4];
        float4 xv3 = xs[w][3][k4];
#pragma unroll
        for (int kk = 0; kk < 4; ++kk) {
            float2 wv = Ws[k4 * 4 + kk][lane];
            float x0 = ((const float*)&xv0)[kk];
            float x1 = ((const float*)&xv1)[kk];
            float x2 = ((const float*)&xv2)[kk];
            float x3 = ((const float*)&xv3)[kk];
            a00 = fmaf(x0, wv.x, a00); a01 = fmaf(x0, wv.y, a01);
            a10 = fmaf(x1, wv.x, a10); a11 = fmaf(x1, wv.y, a11);
            a20 = fmaf(x2, wv.x, a20); a21 = fmaf(x2, wv.y, a21);
            a30 = fmaf(x3, wv.x, a30); a31 = fmaf(x3, wv.y, a31);
        }
    }
    float accs0[4] = {a00, a10, a20, a30};  // channel `lane`
    float accs1[4] = {a01, a11, a21, a31};  // channel `lane+64`
#pragma unroll
    for (int rr = 0; rr < 4; ++rr) {
        int r = r0 + rr;
        if (r >= n) break;  // wave-uniform
        float h0 = accs0[rr], h1 = accs1[rr];
        float p0 = h0 * as0, p1 = h1 * as1;
        float q0 = h0 * ad0, q1 = h1 * ad1;
#pragma unroll
        for (int m = 1; m < 32; m <<= 1) {
            p0 += __shfl_xor(p0, m);
            p1 += __shfl_xor(p1, m);
            q0 += __shfl_xor(q0, m);
            q1 += __shfl_xor(q1, m);
        }
        hpk[(size_t)r * 64 + lane] = (unsigned int)f2bf(h0) | ((unsigned int)f2bf(h1) << 16);
        if (lane == 0) {
            asrc[r * 4 + 0] = p0; asrc[r * 4 + 2] = p1;
            adst[r * 4 + 0] = q0; adst[r * 4 + 2] = q1;
        } else if (lane == 32) {
            asrc[r * 4 + 1] = p0; asrc[r * 4 + 3] = p1;
            adst[r * 4 + 1] = q0; adst[r * 4 + 3] = q1;
        }
    }
}

// ---------------- K2: init deg=1 (self loop) and zero BN stats ----------------
__global__ void k_init(int* __restrict__ deg, float* __restrict__ stats, int n) {
    int t = blockIdx.x * blockDim.x + threadIdx.x;
    if (t < n) deg[t] = 1;
    if (t < 256) stats[t] = 0.f;
}

// ---------------- K3: histogram of dst ----------------
__global__ void k_hist(const int* __restrict__ dst, int* __restrict__ deg, int E) {
    int t = blockIdx.x * blockDim.x + threadIdx.x;
    if (t < E) atomicAdd(&deg[dst[t]], 1);
}

// ---------------- K4abc: device-wide exclusive scan of deg (1024 elems/block) --
__global__ __launch_bounds__(256) void k_scan_part(const int* __restrict__ deg,
                                                   int* __restrict__ bsum, int n) {
    int idx = blockIdx.x * 1024 + threadIdx.x * 4;
    int4 v = {0, 0, 0, 0};
    if (idx + 3 < n) v = *(const int4*)(deg + idx);
    else {
        if (idx + 0 < n) v.x = deg[idx + 0];
        if (idx + 1 < n) v.y = deg[idx + 1];
        if (idx + 2 < n) v.z = deg[idx + 2];
    }
    int s = v.x + v.y + v.z + v.w;
#pragma unroll
    for (int m = 1; m < 64; m <<= 1) s += __shfl_xor(s, m);
    __shared__ int ws[4];
    if ((threadIdx.x & 63) == 0) ws[threadIdx.x >> 6] = s;
    __syncthreads();
    if (threadIdx.x == 0) bsum[blockIdx.x] = ws[0] + ws[1] + ws[2] + ws[3];
}

__global__ __launch_bounds__(256) void k_scan_tops(int* __restrict__ bsum, int B) {
    __shared__ int lds[256];
    int t = threadIdx.x;
    int v = (t < B) ? bsum[t] : 0;
    lds[t] = v;
    __syncthreads();
    int acc = v;
    for (int ofs = 1; ofs < 256; ofs <<= 1) {
        int u = (t >= ofs) ? lds[t - ofs] : 0;
        __syncthreads();
        acc += u;
        lds[t] = acc;
        __syncthreads();
    }
    if (t < B) bsum[t] = acc - v;  // exclusive block offsets (in place)
}

__global__ __launch_bounds__(256) void k_scan_add(const int* __restrict__ deg,
                                                  const int* __restrict__ bsum,
                                                  int* __restrict__ row_start,
                                                  int* __restrict__ cursor, int n, int total) {
    int t = threadIdx.x;
    int idx = blockIdx.x * 1024 + t * 4;
    int4 v = {0, 0, 0, 0};
    if (idx + 3 < n) v = *(const int4*)(deg + idx);
    else {
        if (idx + 0 < n) v.x = deg[idx + 0];
        if (idx + 1 < n) v.y = deg[idx + 1];
        if (idx + 2 < n) v.z = deg[idx + 2];
    }
    int s = v.x + v.y + v.z + v.w;
    __shared__ int lds[256];
    lds[t] = s;
    __syncthreads();
    int acc = s;
    for (int ofs = 1; ofs < 256; ofs <<= 1) {
        int u = (t >= ofs) ? lds[t - ofs] : 0;
        __syncthreads();
        acc += u;
        lds[t] = acc;
        __syncthreads();
    }
    int excl = bsum[blockIdx.x] + acc - s;
    int4 rs;
    rs.x = excl;
    rs.y = rs.x + v.x;
    rs.z = rs.y + v.y;
    rs.w = rs.z + v.z;
    if (idx + 3 < n) {
        *(int4*)(row_start + idx) = rs;
        *(int4*)(cursor + idx) = rs;
    } else {
        if (idx + 0 < n) { row_start[idx + 0] = rs.x; cursor[idx + 0] = rs.x; }
        if (idx + 1 < n) { row_start[idx + 1] = rs.y; cursor[idx + 1] = rs.y; }
        if (idx + 2 < n) { row_start[idx + 2] = rs.z; cursor[idx + 2] = rs.z; }
    }
    if (blockIdx.x == 0 && t == 0) row_start[n] = total;
}

// ---------------- K5: scatter edges (and self loops) into CSR ----------------
__global__ void k_scatter(const int* __restrict__ src, const int* __restrict__ dst,
                          int* __restrict__ cursor, int* __restrict__ csr, int E, int n) {
    int t = blockIdx.x * blockDim.x + threadIdx.x;
    if (t < E) {
        int d = dst[t];
        int slot = atomicAdd(&cursor[d], 1);
        csr[slot] = src[t];
    } else if (t < E + n) {
        int i = t - E;
        int slot = atomicAdd(&cursor[i], 1);
        csr[slot] = i;
    }
}

// ---------------- K6: per-dst-node online-softmax aggregation + residual + bias
//                      + BN partial stats. One wave per node. ----------------
__global__ __launch_bounds__(256) void k_agg(const unsigned int* __restrict__ hw,
                                             const float* __restrict__ asrc,
                                             const float* __restrict__ adst,
                                             const int* __restrict__ row_start,
                                             const int* __restrict__ csr,
                                             const float* __restrict__ prev,
                                             const float* __restrict__ bias,
                                             float* __restrict__ ypre,
                                             float* __restrict__ stats, int n) {
    const int lane = threadIdx.x & 63;
    const int hh = lane >> 5;  // head selector: chans (lane, lane+64) -> heads (hh, 2+hh)
    int wave = blockIdx.x * 4 + (threadIdx.x >> 6);
    int nw = gridDim.x * 4;
    const float b0 = bias[lane], b1 = bias[64 + lane];
    float bsum0 = 0.f, bsq0 = 0.f, bsum1 = 0.f, bsq1 = 0.f;
    for (int i0 = wave; i0 < n; i0 += nw) {
        int i = __builtin_amdgcn_readfirstlane(i0);
        int e0 = row_start[i], e1 = row_start[i + 1];
        float adx0 = adst[i * 4 + hh];
        float adx1 = adst[i * 4 + 2 + hh];
        float m0 = -1e30f, m1 = -1e30f, s0 = 0.f, s1 = 0.f, acc0 = 0.f, acc1 = 0.f;
        for (int e = e0; e < e1; ++e) {
            int j = csr[e];
            float al0 = leaky(asrc[j * 4 + hh] + adx0);
            float al1 = leaky(asrc[j * 4 + 2 + hh] + adx1);
            unsigned int hp = hw[(size_t)j * 64 + lane];
            float h0 = bf2f((unsigned short)(hp & 0xffffu));
            float h1 = bf2f((unsigned short)(hp >> 16));
            float mn0 = fmaxf(m0, al0);
            float sc0 = __expf(m0 - mn0);
            float p0 = __expf(al0 - mn0);
            s0 = s0 * sc0 + p0;
            acc0 = fmaf(acc0, sc0, p0 * h0);
            m0 = mn0;
            float mn1 = fmaxf(m1, al1);
            float sc1 = __expf(m1 - mn1);
            float p1 = __expf(al1 - mn1);
            s1 = s1 * sc1 + p1;
            acc1 = fmaf(acc1, sc1, p1 * h1);
            m1 = mn1;
        }
        float o0 = acc0 / s0 + b0 + prev[(size_t)i * DIM + lane];
        float o1 = acc1 / s1 + b1 + prev[(size_t)i * DIM + 64 + lane];
        ypre[(size_t)i * DIM + lane] = o0;
        ypre[(size_t)i * DIM + 64 + lane] = o1;
        bsum0 += o0; bsq0 = fmaf(o0, o0, bsq0);
        bsum1 += o1; bsq1 = fmaf(o1, o1, bsq1);
    }
    __shared__ float red[4][256];
    red[0][threadIdx.x] = bsum0;
    red[1][threadIdx.x] = bsq0;
    red[2][threadIdx.x] = bsum1;
    red[3][threadIdx.x] = bsq1;
    __syncthreads();
    if (threadIdx.x < 64) {
        int t = threadIdx.x;
        float v0 = red[0][t] + red[0][t + 64] + red[0][t + 128] + red[0][t + 192];
        float v1 = red[1][t] + red[1][t + 64] + red[1][t + 128] + red[1][t + 192];
        float v2 = red[2][t] + red[2][t + 64] + red[2][t + 128] + red[2][t + 192];
        float v3 = red[3][t] + red[3][t + 64] + red[3][t + 128] + red[3][t + 192];
        atomicAdd(&stats[t], v0);        // sum, channel t
        atomicAdd(&stats[64 + t], v2);   // sum, channel 64+t
        atomicAdd(&stats[128 + t], v1);  // sumsq, channel t
        atomicAdd(&stats[192 + t], v3);  // sumsq, channel 64+t
    }
}

// ---------------- K7: finalize BN scale/shift ----------------
__global__ void k_bnfin(const float* __restrict__ stats, const float* __restrict__ gamma,
                        const float* __restrict__ beta, float* __restrict__ AB, int n) {
    int c = threadIdx.x;  // 128 threads
    float fn = (float)n;
    float mean = stats[c] / fn;
    float var = stats[128 + c] / fn - mean * mean;
    float a = gamma[c] * rsqrtf(var + EPS);
    AB[c] = a;
    AB[128 + c] = beta[c] - mean * a;
}

// ---------------- K8: y = relu(y*A + B), in place, float4 ----------------
__global__ __launch_bounds__(256) void k_final(float* __restrict__ y,
                                               const float* __restrict__ AB, int total4) {
    int t0 = blockIdx.x * blockDim.x + threadIdx.x;
    int stride = gridDim.x * blockDim.x;
    for (int t = t0; t < total4; t += stride) {
        float4 v = ((float4*)y)[t];
        int c0 = (t * 4) & 127;
        v.x = fmaf(v.x, AB[c0 + 0], AB[128 + c0 + 0]);
        v.y = fmaf(v.y, AB[c0 + 1], AB[128 + c0 + 1]);
        v.z = fmaf(v.z, AB[c0 + 2], AB[128 + c0 + 2]);
        v.w = fmaf(v.w, AB[c0 + 3], AB[128 + c0 + 3]);
        v.x = v.x > 0.f ? v.x : 0.f;
        v.y = v.y > 0.f ? v.y : 0.f;
        v.z = v.z > 0.f ? v.z : 0.f;
        v.w = v.w > 0.f ? v.w : 0.f;
        ((float4*)y)[t] = v;
    }
}

extern "C" void kernel_launch(void* const* d_in, const int* in_sizes, int n_in,
                              void* d_out, int out_size, void* d_ws, size_t ws_size,
                              hipStream_t stream) {
    const float* prev  = (const float*)d_in[0];
    const float* x     = (const float*)d_in[1];
    const int*   ei    = (const int*)d_in[2];
    const float* W     = (const float*)d_in[3];
    const float* att_s = (const float*)d_in[4];
    const float* att_d = (const float*)d_in[5];
    const float* bias  = (const float*)d_in[6];
    const float* gamma = (const float*)d_in[7];
    const float* beta  = (const float*)d_in[8];
    const int n = in_sizes[0] / DIM;
    const int E = in_sizes[2] / 2;
    const int* src = ei;
    const int* dst = ei + E;

    char* p = (char*)d_ws;
    auto alloc = [&](size_t bytes) {
        void* q = (void*)p;
        p += (bytes + 255) & ~(size_t)255;
        return q;
    };
    unsigned int* hpk = (unsigned int*)alloc((size_t)n * 64 * 4);
    float* asrc      = (float*)alloc((size_t)n * 4 * 4);
    float* adst      = (float*)alloc((size_t)n * 4 * 4);
    int*   deg       = (int*)alloc((size_t)(n + 1) * 4);
    int*   row_start = (int*)alloc((size_t)(n + 1) * 4);
    int*   cursor    = (int*)alloc((size_t)(n + 1) * 4);
    int*   csr       = (int*)alloc((size_t)(E + n) * 4);
    int*   bsum      = (int*)alloc(1024 * 4);
    float* stats     = (float*)alloc(256 * 4);
    float* AB        = (float*)alloc(256 * 4);
    float* yout      = (float*)d_out;

    int B = (n + 1023) / 1024;  // scan blocks (<=256 for n<=262144)
    k_init<<<dim3((n + 255) / 256), dim3(256), 0, stream>>>(deg, stats, n);
    k_gemm<<<dim3((n + 31) / 32), dim3(512), 0, stream>>>(x, W, att_s, att_d, hpk, asrc, adst, n);
    k_hist<<<dim3((E + 255) / 256), dim3(256), 0, stream>>>(dst, deg, E);
    k_scan_part<<<dim3(B), dim3(256), 0, stream>>>(deg, bsum, n);
    k_scan_tops<<<dim3(1), dim3(256), 0, stream>>>(bsum, B);
    k_scan_add<<<dim3(B), dim3(256), 0, stream>>>(deg, bsum, row_start, cursor, n, E + n);
    k_scatter<<<dim3((E + n + 255) / 256), dim3(256), 0, stream>>>(src, dst, cursor, csr, E, n);
    k_agg<<<dim3(2048), dim3(256), 0, stream>>>(hpk, asrc, adst, row_start, csr, prev, bias, yout, stats, n);
    k_bnfin<<<dim3(1), dim3(128), 0, stream>>>(stats, gamma, beta, AB, n);
    int total4 = n * DIM / 4;
    k_final<<<dim3(2048), dim3(256), 0, stream>>>(yout, AB, total4);
}